// Round 7
// baseline (288.887 us; speedup 1.0000x reference)
//
#include <hip/hip_runtime.h>

// EMA recurrence: s_t = 0.9*s_{t-1} + 0.1*x_t
// x: (T=1024, 32, 1024) fp32, state: (32, 1024) fp32
// out = concat(all states (T,32,1024), final_state (32,1024))
//
// v7: DENSITY. Post-mortems v1..v6: ~2.5-2.8 TB/s ceiling is invariant to
// occupancy, load width, pipeline depth, AND read/write separation (v6:
// pure-read k1 + mixed k2 summed to 92us == v1's 93us). Meanwhile the
// harness's own fillBuffer writes 537 MB DENSE at 6.5 TB/s on this chip.
// Remaining explanation: instantaneous address density. All prior versions
// have waves walking t with <=1KB granules at 128KB stride, scattered over
// 128MB -> DRAM row-buffer thrash. Fix: each block owns HALF a timestep row
// (64KB contiguous; each wave a contiguous 4KB granule) and walks t through
// a dense 1MB chunk.
//   - CHUNK=8, NCHUNK=128, SPLIT=2 -> grid (2,128)=256 blocks of 1024 thr.
//   - exact 3-pass scan: k1 locals L_c (zero-init EMA per chunk, dense read),
//     k_scan chunk-start states S_c = A8*S_{c-1} + L_{c-1} (serial in c but
//     loads independent of the FMA chain -> pipelined), k2 output pass from
//     exact S_c (dense read + dense write).
//   - workspace: L (127 rows) + S (128 rows) = 33.4 MB.

typedef float f32x4 __attribute__((ext_vector_type(4)));

constexpr int T = 1024;
constexpr int C = 32 * 1024;
constexpr int CV = C / 4;           // 8192 f32x4 per timestep row
constexpr int CHUNK = 8;            // timesteps per chunk
constexpr int NCHUNK = T / CHUNK;   // 128
constexpr int SPLIT = 2;            // column halves per row
constexpr int HALF = CV / SPLIT;    // 4096 f32x4 = 64 KB
constexpr int V = 4;                // f32x4 per thread (1024*4 = 4096)
constexpr float A8 = 0.43046721f;   // 0.9^8

// ---- k1: per-chunk local EMA (zero init), dense 1 MB stream per block ----
__global__ __launch_bounds__(1024)
void ExponentialDecay_23708219474744_locals(const f32x4* __restrict__ x4,
                                            f32x4* __restrict__ L4) {
    const int td = threadIdx.x;
    const int c = blockIdx.y;                               // 0..NCHUNK-2
    // wave w owns contiguous [w*256, w*256+256) f32x4 of its half-row
    const int col0 = blockIdx.x * HALF + (td >> 6) * (64 * V) + (td & 63);
    const f32x4* __restrict__ xp = x4 + (size_t)c * CHUNK * CV + col0;

    f32x4 s[V] = {};
    #pragma unroll
    for (int t = 0; t < CHUNK; ++t) {
        #pragma unroll
        for (int j = 0; j < V; ++j) {
            f32x4 v = xp[(size_t)t * CV + j * 64];
            s[j].x = fmaf(s[j].x, 0.9f, v.x * 0.1f);
            s[j].y = fmaf(s[j].y, 0.9f, v.y * 0.1f);
            s[j].z = fmaf(s[j].z, 0.9f, v.z * 0.1f);
            s[j].w = fmaf(s[j].w, 0.9f, v.w * 0.1f);
        }
    }
    #pragma unroll
    for (int j = 0; j < V; ++j)
        L4[(size_t)c * CV + col0 + j * 64] = s[j];
}

// ---- k_scan: S_0 = state; S_c = A8*S_{c-1} + L_{c-1}.  8192 threads. ----
__global__ __launch_bounds__(256)
void ExponentialDecay_23708219474744_scan(const f32x4* __restrict__ state4,
                                          const f32x4* __restrict__ L4,
                                          f32x4* __restrict__ S4) {
    const int col = blockIdx.x * 256 + threadIdx.x;  // 0..CV-1
    f32x4 s = state4[col];
    #pragma unroll 8
    for (int c = 0; c < NCHUNK; ++c) {
        S4[(size_t)c * CV + col] = s;
        if (c < NCHUNK - 1) {
            f32x4 l = L4[(size_t)c * CV + col];   // independent of chain
            s.x = fmaf(s.x, A8, l.x);
            s.y = fmaf(s.y, A8, l.y);
            s.z = fmaf(s.z, A8, l.z);
            s.w = fmaf(s.w, A8, l.w);
        }
    }
}

// ---- k2: output pass from exact chunk-start state, dense read + write ----
__global__ __launch_bounds__(1024)
void ExponentialDecay_23708219474744_kernel(const f32x4* __restrict__ x4,
                                            const f32x4* __restrict__ S4,
                                            f32x4* __restrict__ out4) {
    const int td = threadIdx.x;
    const int c = blockIdx.y;                               // 0..NCHUNK-1
    const int col0 = blockIdx.x * HALF + (td >> 6) * (64 * V) + (td & 63);

    f32x4 s[V];
    #pragma unroll
    for (int j = 0; j < V; ++j)
        s[j] = S4[(size_t)c * CV + col0 + j * 64];

    const f32x4* __restrict__ xp = x4 + (size_t)c * CHUNK * CV + col0;
    f32x4* __restrict__ op = out4 + (size_t)c * CHUNK * CV + col0;

    #pragma unroll
    for (int t = 0; t < CHUNK; ++t) {
        #pragma unroll
        for (int j = 0; j < V; ++j) {
            f32x4 v = xp[(size_t)t * CV + j * 64];
            s[j].x = fmaf(s[j].x, 0.9f, v.x * 0.1f);
            s[j].y = fmaf(s[j].y, 0.9f, v.y * 0.1f);
            s[j].z = fmaf(s[j].z, 0.9f, v.z * 0.1f);
            s[j].w = fmaf(s[j].w, 0.9f, v.w * 0.1f);
            op[(size_t)t * CV + j * 64] = s[j];
        }
    }

    if (c == NCHUNK - 1) {
        #pragma unroll
        for (int j = 0; j < V; ++j)
            out4[(size_t)T * CV + col0 + j * 64] = s[j];   // final_state
    }
}

extern "C" void kernel_launch(void* const* d_in, const int* in_sizes, int n_in,
                              void* d_out, int out_size, void* d_ws, size_t ws_size,
                              hipStream_t stream) {
    const f32x4* x = (const f32x4*)d_in[0];
    const f32x4* state = (const f32x4*)d_in[1];
    f32x4* out = (f32x4*)d_out;
    f32x4* L = (f32x4*)d_ws;                       // 127 rows * 128 KB
    f32x4* S = L + (size_t)(NCHUNK - 1) * CV;      // 128 rows * 128 KB

    dim3 blk(1024);
    dim3 g1(SPLIT, NCHUNK - 1);   // (2,127)
    ExponentialDecay_23708219474744_locals<<<g1, blk, 0, stream>>>(x, L);

    ExponentialDecay_23708219474744_scan<<<dim3(CV / 256), dim3(256), 0, stream>>>(state, L, S);

    dim3 g2(SPLIT, NCHUNK);       // (2,128)
    ExponentialDecay_23708219474744_kernel<<<g2, blk, 0, stream>>>(x, S, out);
}

// Round 8
// 257.729 us; speedup vs baseline: 1.1209x; 1.1209x over previous
//
#include <hip/hip_runtime.h>

// EMA recurrence: s_t = 0.9*s_{t-1} + 0.1*x_t
// x: (T=1024, 32, 1024) fp32, state: (32, 1024) fp32
// out = concat(all states (T,32,1024), final_state (32,1024))
//
// v8 = v6 + ONE variable: nontemporal out-stores in k2.
// Model (fits v1..v7): reads cap ~2.5 TB/s on this box (needs >=4MB in
// flight; insensitive to waves/width/depth/density beyond that), writes
// sustain ~6.5 TB/s (harness fill measured on-box). v6's k2 re-read x from
// HBM because its own 131 MB out stream evicted x from L3. nt stores keep
// out from allocating in L3 -> x stays L3-resident after k1 -> k2 reads hit
// Infinity Cache and k2 drops toward write-bound.
// Everything else is byte-identical to v6 (exact two-pass scan, no warm-up
// truncation; L workspace 1.92 MB, normal stores for L since the Horner
// prologue re-reads it from L2).

typedef float f32x4 __attribute__((ext_vector_type(4)));

constexpr int T = 1024;
constexpr int C = 32 * 1024;
constexpr int CV = C / 4;          // 8192 float4 columns per timestep
constexpr int CHUNK = 64;
constexpr int NCHUNK = T / CHUNK;  // 16
constexpr float A64 = 1.1790184577738602e-3f;  // 0.9^64

// ---------------- kernel 1: per-chunk local EMA (zero-init), chunks 0..14 ---
__global__ __launch_bounds__(256)
void ExponentialDecay_23708219474744_locals(const f32x4* __restrict__ x4,
                                            f32x4* __restrict__ L) {
    const int cv = blockIdx.x * blockDim.x + threadIdx.x;  // 0..CV-1
    const int c = blockIdx.y;                              // 0..NCHUNK-2
    const f32x4* __restrict__ xp = x4 + (size_t)c * CHUNK * CV + cv;

    const float a = 0.9f, oma = 0.1f;
    f32x4 s = {0.0f, 0.0f, 0.0f, 0.0f};
    #pragma unroll 8
    for (int t = 0; t < CHUNK; ++t) {
        f32x4 v = xp[(size_t)t * CV];
        s.x = fmaf(s.x, a, v.x * oma);
        s.y = fmaf(s.y, a, v.y * oma);
        s.z = fmaf(s.z, a, v.z * oma);
        s.w = fmaf(s.w, a, v.w * oma);
    }
    L[(size_t)c * CV + cv] = s;   // normal store: L is re-read by k2's Horner
}

// ---------------- kernel 2: exact start state via Horner, then stream out ---
__global__ __launch_bounds__(256)
void ExponentialDecay_23708219474744_kernel(const f32x4* __restrict__ x4,
                                            const f32x4* __restrict__ state4,
                                            const f32x4* __restrict__ L,
                                            f32x4* __restrict__ out4) {
    const int cv = blockIdx.x * blockDim.x + threadIdx.x;  // 0..CV-1
    const int c = blockIdx.y;                              // 0..NCHUNK-1
    const float a = 0.9f, oma = 0.1f;

    // S_c = A^c * s0 + sum_{j<c} A^{c-1-j} * L_j   (Horner, exact chain)
    f32x4 s = state4[cv];
    for (int j = 0; j < c; ++j) {
        f32x4 l = L[(size_t)j * CV + cv];
        s.x = fmaf(s.x, A64, l.x);
        s.y = fmaf(s.y, A64, l.y);
        s.z = fmaf(s.z, A64, l.z);
        s.w = fmaf(s.w, A64, l.w);
    }

    const f32x4* __restrict__ xp = x4 + (size_t)c * CHUNK * CV + cv;
    f32x4* __restrict__ op = out4 + (size_t)c * CHUNK * CV + cv;

    #pragma unroll 8
    for (int t = 0; t < CHUNK; ++t) {
        f32x4 v = xp[(size_t)t * CV];
        s.x = fmaf(s.x, a, v.x * oma);
        s.y = fmaf(s.y, a, v.y * oma);
        s.z = fmaf(s.z, a, v.z * oma);
        s.w = fmaf(s.w, a, v.w * oma);
        __builtin_nontemporal_store(s, op + (size_t)t * CV);  // keep x in L3
    }

    if (c == NCHUNK - 1) {
        __builtin_nontemporal_store(s, out4 + (size_t)T * CV + cv);  // final_state
    }
}

extern "C" void kernel_launch(void* const* d_in, const int* in_sizes, int n_in,
                              void* d_out, int out_size, void* d_ws, size_t ws_size,
                              hipStream_t stream) {
    const f32x4* x = (const f32x4*)d_in[0];
    const f32x4* state = (const f32x4*)d_in[1];
    f32x4* out = (f32x4*)d_out;
    f32x4* L = (f32x4*)d_ws;  // (NCHUNK-1) * C floats = 1.92 MB workspace

    dim3 block(256);
    dim3 grid1(CV / 256, NCHUNK - 1);  // (32, 15): chunks 0..14
    ExponentialDecay_23708219474744_locals<<<grid1, block, 0, stream>>>(x, L);

    dim3 grid2(CV / 256, NCHUNK);      // (32, 16)
    ExponentialDecay_23708219474744_kernel<<<grid2, block, 0, stream>>>(x, state, L, out);
}